// Round 2
// baseline (763.458 us; speedup 1.0000x reference)
//
#include <hip/hip_runtime.h>
#include <hip/hip_bf16.h>

#define NASP 5
#define H1 10
#define SEQ 500
#define EMB 300
#define NCOL 52          // padded 5*10 -> 52 (cols 50,51 zero)
#define THREADS 512
#define DSTR 20          // doc LDS row stride (floats), 16-col chunk + 4 pad
#define NE4 75           // EMB/4
#define W3_FLOATS (NE4 * 13 * 16)   // 15600 floats = 62.4 KB

// ---- prep: repack W[5][300][10] -> W3[e4][j4][r][c] (16 contiguous floats per (e4,j4)) ----
// col = j4*4+c in [0,52); a=col/10, h=col%10; value = W[a][e4*4+r][h], 0 if col>=50.
__global__ void build_w3(const float* __restrict__ Wg, float* __restrict__ W3) {
    int i = blockIdx.x * blockDim.x + threadIdx.x;
    if (i >= W3_FLOATS) return;
    int c  = i & 3;
    int r  = (i >> 2) & 3;
    int j4 = (i >> 4) % 13;
    int e4 = i / (13 * 16);
    int col = j4 * 4 + c;
    float v = 0.f;
    if (col < 50) {
        int a = col / 10, h = col - a * 10;
        v = Wg[a * (EMB * H1) + (e4 * 4 + r) * H1 + h];
    }
    W3[i] = v;
}

__global__ __launch_bounds__(THREADS, 6)
void arl_fused(const float* __restrict__ doc,
               const float* __restrict__ W3,     // [75][13][16] repacked weights
               const float* __restrict__ embG,   // [5][30]
               float* __restrict__ out,
               int B) {
    __shared__ float SB[SEQ * DSTR];             // 10000 floats = 40 KB

    const int tid  = threadIdx.x;
    const int b    = blockIdx.x;
    const int s    = tid;
    const bool active = (s < SEQ);
    const int lane = tid & 63;
    const int wave = tid >> 6;
    const int srow = active ? s : (SEQ - 1);     // clamp; extra threads compute garbage, never write

    const float* docB = doc + (size_t)b * (SEQ * EMB);

    float acc[NCOL];
    #pragma unroll
    for (int j = 0; j < NCOL; ++j) acc[j] = 0.f;

    // ---------------- phase 1: proj = doc x W; proj kept in registers ----------------
    // 19 chunks: 18 x 16 e-cols + 1 x 12. W comes from global via uniform (scalar) loads.
    for (int chunk = 0; chunk < 19; ++chunk) {
        const int e0  = chunk * 16;
        const int nf4 = (chunk < 18) ? 4 : 3;

        // stage doc tile [500][nf4*4] -> SB rows of stride 20 (float4, coalesced-ish)
        if (nf4 == 4) {
            for (int q = tid; q < SEQ * 4; q += THREADS) {
                int sr = q >> 2, c4 = q & 3;
                float4 v = *reinterpret_cast<const float4*>(docB + sr * EMB + e0 + (c4 << 2));
                *reinterpret_cast<float4*>(&SB[sr * DSTR + (c4 << 2)]) = v;
            }
        } else {
            for (int q = tid; q < SEQ * 3; q += THREADS) {
                int sr = q / 3, c4 = q - sr * 3;
                float4 v = *reinterpret_cast<const float4*>(docB + sr * EMB + e0 + (c4 << 2));
                *reinterpret_cast<float4*>(&SB[sr * DSTR + (c4 << 2)]) = v;
            }
        }
        __syncthreads();

        for (int l4 = 0; l4 < nf4; ++l4) {
            const int e4 = chunk * 4 + l4;
            float4 d = *reinterpret_cast<const float4*>(&SB[srow * DSTR + (l4 << 2)]);
            const float* __restrict__ wb = W3 + e4 * (13 * 16);   // uniform address
            #pragma unroll
            for (int j4 = 0; j4 < 13; ++j4) {
                const float* __restrict__ w = wb + j4 * 16;       // 16 floats: [r][c]
                const int cc = j4 * 4;
                acc[cc+0] = fmaf(d.x, w[0],  acc[cc+0]);
                acc[cc+1] = fmaf(d.x, w[1],  acc[cc+1]);
                acc[cc+2] = fmaf(d.x, w[2],  acc[cc+2]);
                acc[cc+3] = fmaf(d.x, w[3],  acc[cc+3]);
                acc[cc+0] = fmaf(d.y, w[4],  acc[cc+0]);
                acc[cc+1] = fmaf(d.y, w[5],  acc[cc+1]);
                acc[cc+2] = fmaf(d.y, w[6],  acc[cc+2]);
                acc[cc+3] = fmaf(d.y, w[7],  acc[cc+3]);
                acc[cc+0] = fmaf(d.z, w[8],  acc[cc+0]);
                acc[cc+1] = fmaf(d.z, w[9],  acc[cc+1]);
                acc[cc+2] = fmaf(d.z, w[10], acc[cc+2]);
                acc[cc+3] = fmaf(d.z, w[11], acc[cc+3]);
                acc[cc+0] = fmaf(d.w, w[12], acc[cc+0]);
                acc[cc+1] = fmaf(d.w, w[13], acc[cc+1]);
                acc[cc+2] = fmaf(d.w, w[14], acc[cc+2]);
                acc[cc+3] = fmaf(d.w, w[15], acc[cc+3]);
            }
        }
        __syncthreads();
    }

    // ---------------- phase 2: scores, softmax, pooling (per-aspect, low VGPR) -------
    float* Ub  = &SB[0];      // [513]  u shifted: read at [s] -> u[s-1]
    float* Wb  = &SB[520];    // [504]  w: read at [s+1] -> w[s+1]
    float* red = &SB[1032];   // [8*10]

    #pragma unroll 1
    for (int a = 0; a < NASP; ++a) {
        // u/v/w partial dots (emb reads are uniform -> scalar loads)
        float su = 0.f, sv = 0.f, sw = 0.f;
        #pragma unroll
        for (int h = 0; h < H1; ++h) {
            float pj = acc[a * 10 + h];
            su = fmaf(pj, embG[a * 30 + h],      su);
            sv = fmaf(pj, embG[a * 30 + 10 + h], sv);
            sw = fmaf(pj, embG[a * 30 + 20 + h], sw);
        }
        __syncthreads();                       // previous aspect done with Ub/Wb
        if (active) { Ub[s + 1] = su; Wb[s] = sw; }
        if (tid == 0) { Ub[0] = 0.f; Wb[SEQ] = 0.f; }
        __syncthreads();

        float sc = active ? (Ub[s] + sv + Wb[s + 1]) : -1e30f;

        // block max
        float x = sc;
        #pragma unroll
        for (int off = 32; off > 0; off >>= 1) x = fmaxf(x, __shfl_xor(x, off));
        if (lane == 0) red[wave] = x;
        __syncthreads();
        float m = red[0];
        #pragma unroll
        for (int w2 = 1; w2 < 8; ++w2) m = fmaxf(m, red[w2]);
        __syncthreads();

        // exp + block sum
        float p = active ? __expf(sc - m) : 0.f;
        float t = p;
        #pragma unroll
        for (int off = 32; off > 0; off >>= 1) t += __shfl_xor(t, off);
        if (lane == 0) red[wave] = t;
        __syncthreads();
        float ssum = 0.f;
        #pragma unroll
        for (int w2 = 0; w2 < 8; ++w2) ssum += red[w2];
        float attnv = p / ssum;

        if (active) out[((size_t)b * NASP + a) * SEQ + s] = attnv;
        __syncthreads();                       // red about to be reused

        // rep[a][h] = sum_s proj*attn
        #pragma unroll
        for (int h = 0; h < H1; ++h) {
            float xx = acc[a * 10 + h] * attnv;
            #pragma unroll
            for (int off = 32; off > 0; off >>= 1) xx += __shfl_xor(xx, off);
            if (lane == 0) red[wave * 10 + h] = xx;
        }
        __syncthreads();
        if (tid < H1) {
            float rs = 0.f;
            #pragma unroll
            for (int w2 = 0; w2 < 8; ++w2) rs += red[w2 * 10 + tid];
            out[(size_t)B * NASP * SEQ + (size_t)b * 50 + a * 10 + tid] = rs;
        }
    }
}

extern "C" void kernel_launch(void* const* d_in, const int* in_sizes, int n_in,
                              void* d_out, int out_size, void* d_ws, size_t ws_size,
                              hipStream_t stream) {
    const float* doc = (const float*)d_in[0];
    const float* Wg  = (const float*)d_in[1];
    const float* emb = (const float*)d_in[2];
    float* out = (float*)d_out;
    float* W3  = (float*)d_ws;                 // 62.4 KB scratch
    const int B = in_sizes[0] / (SEQ * EMB);   // 1024

    build_w3<<<dim3((W3_FLOATS + 255) / 256), dim3(256), 0, stream>>>(Wg, W3);
    arl_fused<<<dim3(B), dim3(THREADS), 0, stream>>>(doc, W3, emb, out, B);
}

// Round 3
// 758.683 us; speedup vs baseline: 1.0063x; 1.0063x over previous
//
#include <hip/hip_runtime.h>
#include <hip/hip_bf16.h>

#define NASP 5
#define H1 10
#define SEQ 500
#define EMB 300
#define NCOL 52          // padded 5*10 -> 52 (cols 50,51 zero)
#define THREADS 512
#define NE4 75           // EMB/4
#define W3_FLOATS (NE4 * 13 * 16)   // 15600 floats = 62.4 KB

// ---- prep: repack W[5][300][10] -> W3[e4][j4][r][c] (16 contiguous floats per (e4,j4)) ----
// col = j4*4+c in [0,52); a=col/10, h=col%10; value = W[a][e4*4+r][h], 0 if col>=50.
__global__ void build_w3(const float* __restrict__ Wg, float* __restrict__ W3) {
    int i = blockIdx.x * blockDim.x + threadIdx.x;
    if (i >= W3_FLOATS) return;
    int c  = i & 3;
    int r  = (i >> 2) & 3;
    int j4 = (i >> 4) % 13;
    int e4 = i / (13 * 16);
    int col = j4 * 4 + c;
    float v = 0.f;
    if (col < 50) {
        int a = col / 10, h = col - a * 10;
        v = Wg[a * (EMB * H1) + (e4 * 4 + r) * H1 + h];
    }
    W3[i] = v;
}

__global__ __launch_bounds__(THREADS, 4)
void arl_fused(const float* __restrict__ doc,
               const float* __restrict__ W3,     // [75][13][16] repacked weights
               const float* __restrict__ embG,   // [5][30]
               float* __restrict__ out,
               int B) {
    __shared__ float SB[16 * SEQ];               // 8000 floats = 32 KB, plane layout [c][s]

    const int tid  = threadIdx.x;
    const int b    = blockIdx.x;
    const int s    = tid;
    const bool active = (s < SEQ);
    const int lane = tid & 63;
    const int wave = tid >> 6;
    const int srow = active ? s : (SEQ - 1);     // clamp; extra threads compute garbage, never write

    const float* docB = doc + (size_t)b * (SEQ * EMB);

    float acc[NCOL];
    #pragma unroll
    for (int j = 0; j < NCOL; ++j) acc[j] = 0.f;

    // ---------------- phase 1: proj = doc x W; proj kept in registers ----------------
    // 19 chunks: 18 x 16 e-cols + 1 x 12. Doc tile in LDS planes SB[c][s] (conflict-free
    // b32 reads). W via wave-uniform (scalar) loads from repacked W3.
    for (int chunk = 0; chunk < 19; ++chunk) {
        const int e0  = chunk * 16;
        const int nf4 = (chunk < 18) ? 4 : 3;

        if (nf4 == 4) {
            for (int q = tid; q < SEQ * 4; q += THREADS) {
                int sr = q >> 2, c4 = q & 3;
                float4 v = *reinterpret_cast<const float4*>(docB + sr * EMB + e0 + (c4 << 2));
                SB[((c4 << 2) + 0) * SEQ + sr] = v.x;
                SB[((c4 << 2) + 1) * SEQ + sr] = v.y;
                SB[((c4 << 2) + 2) * SEQ + sr] = v.z;
                SB[((c4 << 2) + 3) * SEQ + sr] = v.w;
            }
        } else {
            for (int q = tid; q < SEQ * 3; q += THREADS) {
                int sr = q / 3, c4 = q - sr * 3;
                float4 v = *reinterpret_cast<const float4*>(docB + sr * EMB + e0 + (c4 << 2));
                SB[((c4 << 2) + 0) * SEQ + sr] = v.x;
                SB[((c4 << 2) + 1) * SEQ + sr] = v.y;
                SB[((c4 << 2) + 2) * SEQ + sr] = v.z;
                SB[((c4 << 2) + 3) * SEQ + sr] = v.w;
            }
        }
        __syncthreads();

        for (int l4 = 0; l4 < nf4; ++l4) {
            const int e4 = chunk * 4 + l4;
            const float dx = SB[((l4 << 2) + 0) * SEQ + srow];
            const float dy = SB[((l4 << 2) + 1) * SEQ + srow];
            const float dz = SB[((l4 << 2) + 2) * SEQ + srow];
            const float dw = SB[((l4 << 2) + 3) * SEQ + srow];
            const float* __restrict__ wb = W3 + e4 * (13 * 16);   // uniform address -> s_load
            #pragma unroll
            for (int j4 = 0; j4 < 13; ++j4) {
                const float* __restrict__ w = wb + j4 * 16;       // 16 floats: [r][c]
                const int cc = j4 * 4;
                acc[cc+0] = fmaf(dx, w[0],  acc[cc+0]);
                acc[cc+1] = fmaf(dx, w[1],  acc[cc+1]);
                acc[cc+2] = fmaf(dx, w[2],  acc[cc+2]);
                acc[cc+3] = fmaf(dx, w[3],  acc[cc+3]);
                acc[cc+0] = fmaf(dy, w[4],  acc[cc+0]);
                acc[cc+1] = fmaf(dy, w[5],  acc[cc+1]);
                acc[cc+2] = fmaf(dy, w[6],  acc[cc+2]);
                acc[cc+3] = fmaf(dy, w[7],  acc[cc+3]);
                acc[cc+0] = fmaf(dz, w[8],  acc[cc+0]);
                acc[cc+1] = fmaf(dz, w[9],  acc[cc+1]);
                acc[cc+2] = fmaf(dz, w[10], acc[cc+2]);
                acc[cc+3] = fmaf(dz, w[11], acc[cc+3]);
                acc[cc+0] = fmaf(dw, w[12], acc[cc+0]);
                acc[cc+1] = fmaf(dw, w[13], acc[cc+1]);
                acc[cc+2] = fmaf(dw, w[14], acc[cc+2]);
                acc[cc+3] = fmaf(dw, w[15], acc[cc+3]);
            }
        }
        __syncthreads();
    }

    // ---------------- phase 2: scores, softmax, pooling (per-aspect, low VGPR) -------
    float* Ub  = &SB[0];      // [513]  u shifted: read at [s] -> u[s-1]
    float* Wb  = &SB[520];    // [504]  w: read at [s+1] -> w[s+1]
    float* red = &SB[1032];   // [8*10]

    #pragma unroll 1
    for (int a = 0; a < NASP; ++a) {
        // u/v/w partial dots (emb reads are uniform -> scalar loads)
        float su = 0.f, sv = 0.f, sw = 0.f;
        #pragma unroll
        for (int h = 0; h < H1; ++h) {
            float pj = acc[a * 10 + h];
            su = fmaf(pj, embG[a * 30 + h],      su);
            sv = fmaf(pj, embG[a * 30 + 10 + h], sv);
            sw = fmaf(pj, embG[a * 30 + 20 + h], sw);
        }
        __syncthreads();                       // previous aspect done with Ub/Wb
        if (active) { Ub[s + 1] = su; Wb[s] = sw; }
        if (tid == 0) { Ub[0] = 0.f; Wb[SEQ] = 0.f; }
        __syncthreads();

        float sc = active ? (Ub[s] + sv + Wb[s + 1]) : -1e30f;

        // block max
        float x = sc;
        #pragma unroll
        for (int off = 32; off > 0; off >>= 1) x = fmaxf(x, __shfl_xor(x, off));
        if (lane == 0) red[wave] = x;
        __syncthreads();
        float m = red[0];
        #pragma unroll
        for (int w2 = 1; w2 < 8; ++w2) m = fmaxf(m, red[w2]);
        __syncthreads();

        // exp + block sum
        float p = active ? __expf(sc - m) : 0.f;
        float t = p;
        #pragma unroll
        for (int off = 32; off > 0; off >>= 1) t += __shfl_xor(t, off);
        if (lane == 0) red[wave] = t;
        __syncthreads();
        float ssum = 0.f;
        #pragma unroll
        for (int w2 = 0; w2 < 8; ++w2) ssum += red[w2];
        float attnv = p / ssum;

        if (active) out[((size_t)b * NASP + a) * SEQ + s] = attnv;
        __syncthreads();                       // red about to be reused

        // rep[a][h] = sum_s proj*attn
        #pragma unroll
        for (int h = 0; h < H1; ++h) {
            float xx = acc[a * 10 + h] * attnv;
            #pragma unroll
            for (int off = 32; off > 0; off >>= 1) xx += __shfl_xor(xx, off);
            if (lane == 0) red[wave * 10 + h] = xx;
        }
        __syncthreads();
        if (tid < H1) {
            float rs = 0.f;
            #pragma unroll
            for (int w2 = 0; w2 < 8; ++w2) rs += red[w2 * 10 + tid];
            out[(size_t)B * NASP * SEQ + (size_t)b * 50 + a * 10 + tid] = rs;
        }
    }
}

extern "C" void kernel_launch(void* const* d_in, const int* in_sizes, int n_in,
                              void* d_out, int out_size, void* d_ws, size_t ws_size,
                              hipStream_t stream) {
    const float* doc = (const float*)d_in[0];
    const float* Wg  = (const float*)d_in[1];
    const float* emb = (const float*)d_in[2];
    float* out = (float*)d_out;
    float* W3  = (float*)d_ws;                 // 62.4 KB scratch
    const int B = in_sizes[0] / (SEQ * EMB);   // 1024

    build_w3<<<dim3((W3_FLOATS + 255) / 256), dim3(256), 0, stream>>>(Wg, W3);
    arl_fused<<<dim3(B), dim3(THREADS), 0, stream>>>(doc, W3, emb, out, B);
}

// Round 4
// 670.654 us; speedup vs baseline: 1.1384x; 1.1313x over previous
//
#include <hip/hip_runtime.h>
#include <hip/hip_bf16.h>

#define NASP 5
#define H1 10
#define SEQ 500
#define EMB 300
#define NCOL 52          // padded 5*10 -> 52 (cols 50,51 zero)
#define THREADS 512
#define DSTR 36          // doc LDS row stride (floats); 144 B rows, 16B-aligned
#define NE4 75           // EMB/4
#define W3_FLOATS (NE4 * 13 * 16)   // 15600 floats = 62.4 KB

// ---- prep: repack W[5][300][10] -> W3[e4][j4][r][c] (16 contiguous floats per (e4,j4)) ----
// col = j4*4+c in [0,52); a=col/10, h=col%10; value = W[a][e4*4+r][h], 0 if col>=50.
__global__ void build_w3(const float* __restrict__ Wg, float* __restrict__ W3) {
    int i = blockIdx.x * blockDim.x + threadIdx.x;
    if (i >= W3_FLOATS) return;
    int c  = i & 3;
    int r  = (i >> 2) & 3;
    int j4 = (i >> 4) % 13;
    int e4 = i / (13 * 16);
    int col = j4 * 4 + c;
    float v = 0.f;
    if (col < 50) {
        int a = col / 10, h = col - a * 10;
        v = Wg[a * (EMB * H1) + (e4 * 4 + r) * H1 + h];
    }
    W3[i] = v;
}

__global__ __launch_bounds__(THREADS, 4)
void arl_fused(const float* __restrict__ doc,
               const float* __restrict__ W3,     // [75][13][16] repacked weights
               const float* __restrict__ embG,   // [5][30]
               float* __restrict__ out,
               int B) {
    __shared__ float SB[SEQ * DSTR];             // 18000 floats = 72 KB

    const int tid  = threadIdx.x;
    const int b    = blockIdx.x;
    const int s    = tid;
    const bool active = (s < SEQ);
    const int lane = tid & 63;
    const int wave = tid >> 6;
    const int srow = active ? s : (SEQ - 1);     // clamp; extra threads compute garbage, never write

    const float* docB = doc + (size_t)b * (SEQ * EMB);

    float acc[NCOL];
    #pragma unroll
    for (int j = 0; j < NCOL; ++j) acc[j] = 0.f;

    // ---------------- phase 1: proj = doc x W; proj kept in registers ----------------
    // 10 chunks: 9 x 32 e-cols (128 B per row -> full-line fetches) + 1 x 12.
    // Doc tile in LDS [500][36]; W via wave-uniform scalar loads from repacked W3.
    for (int chunk = 0; chunk < 10; ++chunk) {
        const int e0  = chunk * 32;
        const int nf4 = (chunk < 9) ? 8 : 3;

        if (nf4 == 8) {
            for (int q = tid; q < SEQ * 8; q += THREADS) {
                int sr = q >> 3, c4 = q & 7;
                float4 v = *reinterpret_cast<const float4*>(docB + sr * EMB + e0 + (c4 << 2));
                *reinterpret_cast<float4*>(&SB[sr * DSTR + (c4 << 2)]) = v;
            }
        } else {
            for (int q = tid; q < SEQ * 3; q += THREADS) {
                int sr = q / 3, c4 = q - sr * 3;
                float4 v = *reinterpret_cast<const float4*>(docB + sr * EMB + e0 + (c4 << 2));
                *reinterpret_cast<float4*>(&SB[sr * DSTR + (c4 << 2)]) = v;
            }
        }
        __syncthreads();

        for (int l4 = 0; l4 < nf4; ++l4) {
            const int e4 = chunk * 8 + l4;
            float4 d = *reinterpret_cast<const float4*>(&SB[srow * DSTR + (l4 << 2)]);
            const float* __restrict__ wb = W3 + e4 * (13 * 16);   // uniform address -> s_load
            #pragma unroll
            for (int j4 = 0; j4 < 13; ++j4) {
                const float* __restrict__ w = wb + j4 * 16;       // 16 floats: [r][c]
                const int cc = j4 * 4;
                acc[cc+0] = fmaf(d.x, w[0],  acc[cc+0]);
                acc[cc+1] = fmaf(d.x, w[1],  acc[cc+1]);
                acc[cc+2] = fmaf(d.x, w[2],  acc[cc+2]);
                acc[cc+3] = fmaf(d.x, w[3],  acc[cc+3]);
                acc[cc+0] = fmaf(d.y, w[4],  acc[cc+0]);
                acc[cc+1] = fmaf(d.y, w[5],  acc[cc+1]);
                acc[cc+2] = fmaf(d.y, w[6],  acc[cc+2]);
                acc[cc+3] = fmaf(d.y, w[7],  acc[cc+3]);
                acc[cc+0] = fmaf(d.z, w[8],  acc[cc+0]);
                acc[cc+1] = fmaf(d.z, w[9],  acc[cc+1]);
                acc[cc+2] = fmaf(d.z, w[10], acc[cc+2]);
                acc[cc+3] = fmaf(d.z, w[11], acc[cc+3]);
                acc[cc+0] = fmaf(d.w, w[12], acc[cc+0]);
                acc[cc+1] = fmaf(d.w, w[13], acc[cc+1]);
                acc[cc+2] = fmaf(d.w, w[14], acc[cc+2]);
                acc[cc+3] = fmaf(d.w, w[15], acc[cc+3]);
            }
        }
        __syncthreads();
    }

    // ---------------- phase 2: scores, softmax, pooling (fully unrolled: acc indices
    // must stay compile-time constant or acc[52] is demoted to scratch!) --------------
    float* embS  = &SB[0];      // 150 floats
    float* Ubuf  = &SB[160];    // 5 * 513
    float* W3buf = &SB[2725];   // 5 * 501
    float* red   = &SB[5232];   // 8 * 52

    if (tid < NASP * 3 * H1) embS[tid] = embG[tid];
    __syncthreads();

    // u/v/w partial dots against the 3 context slots of the aspect embedding
    float uu[NASP], vv[NASP], ww[NASP];
    #pragma unroll
    for (int a = 0; a < NASP; ++a) {
        float su = 0.f, sv = 0.f, sw = 0.f;
        #pragma unroll
        for (int h = 0; h < H1; ++h) {
            float pj = acc[a * 10 + h];
            su = fmaf(pj, embS[a * 30 + h],       su);
            sv = fmaf(pj, embS[a * 30 + 10 + h],  sv);
            sw = fmaf(pj, embS[a * 30 + 20 + h],  sw);
        }
        uu[a] = su; vv[a] = sv; ww[a] = sw;
    }
    if (active) {
        #pragma unroll
        for (int a = 0; a < NASP; ++a) {
            Ubuf[a * 513 + s + 1] = uu[a];   // read back at [s] -> u[s-1]
            W3buf[a * 501 + s]    = ww[a];   // read back at [s+1] -> w[s+1]
        }
    }
    if (tid == 0) {
        #pragma unroll
        for (int a = 0; a < NASP; ++a) { Ubuf[a * 513] = 0.f; W3buf[a * 501 + 500] = 0.f; }
    }
    __syncthreads();

    float sc[NASP];
    #pragma unroll
    for (int a = 0; a < NASP; ++a)
        sc[a] = active ? (Ubuf[a * 513 + s] + vv[a] + W3buf[a * 501 + s + 1]) : -1e30f;

    // block-wide max per aspect
    float m[NASP];
    #pragma unroll
    for (int a = 0; a < NASP; ++a) {
        float x = sc[a];
        #pragma unroll
        for (int off = 32; off > 0; off >>= 1) x = fmaxf(x, __shfl_xor(x, off));
        if (lane == 0) red[wave * NASP + a] = x;
    }
    __syncthreads();
    #pragma unroll
    for (int a = 0; a < NASP; ++a) {
        float mm = red[a];
        #pragma unroll
        for (int w2 = 1; w2 < 8; ++w2) mm = fmaxf(mm, red[w2 * NASP + a]);
        m[a] = mm;
    }
    __syncthreads();

    // exp + block-wide sum per aspect
    float p[NASP];
    #pragma unroll
    for (int a = 0; a < NASP; ++a) {
        float x = active ? __expf(sc[a] - m[a]) : 0.f;
        p[a] = x;
        float t = x;
        #pragma unroll
        for (int off = 32; off > 0; off >>= 1) t += __shfl_xor(t, off);
        if (lane == 0) red[wave * NASP + a] = t;
    }
    __syncthreads();
    float attnv[NASP];
    #pragma unroll
    for (int a = 0; a < NASP; ++a) {
        float ssum = 0.f;
        #pragma unroll
        for (int w2 = 0; w2 < 8; ++w2) ssum += red[w2 * NASP + a];
        attnv[a] = p[a] / ssum;
    }

    // write attention output [B][5][500]
    if (active) {
        #pragma unroll
        for (int a = 0; a < NASP; ++a)
            out[((size_t)b * NASP + a) * SEQ + s] = attnv[a];
    }
    __syncthreads();   // red about to be reused for pooling

    // rep[a][h] = sum_s proj * attn  (block reduction of 50 values)
    #pragma unroll
    for (int j = 0; j < 50; ++j) {
        float x = acc[j] * attnv[j / 10];
        #pragma unroll
        for (int off = 32; off > 0; off >>= 1) x += __shfl_xor(x, off);
        if (lane == 0) red[wave * 52 + j] = x;
    }
    __syncthreads();
    if (tid < 50) {
        float ssum = 0.f;
        #pragma unroll
        for (int w2 = 0; w2 < 8; ++w2) ssum += red[w2 * 52 + tid];
        out[(size_t)B * NASP * SEQ + (size_t)b * 50 + tid] = ssum;
    }
}

extern "C" void kernel_launch(void* const* d_in, const int* in_sizes, int n_in,
                              void* d_out, int out_size, void* d_ws, size_t ws_size,
                              hipStream_t stream) {
    const float* doc = (const float*)d_in[0];
    const float* Wg  = (const float*)d_in[1];
    const float* emb = (const float*)d_in[2];
    float* out = (float*)d_out;
    float* W3  = (float*)d_ws;                 // 62.4 KB scratch
    const int B = in_sizes[0] / (SEQ * EMB);   // 1024

    build_w3<<<dim3((W3_FLOATS + 255) / 256), dim3(256), 0, stream>>>(Wg, W3);
    arl_fused<<<dim3(B), dim3(THREADS), 0, stream>>>(doc, W3, emb, out, B);
}

// Round 5
// 229.953 us; speedup vs baseline: 3.3201x; 2.9165x over previous
//
#include <hip/hip_runtime.h>
#include <hip/hip_bf16.h>

#define NASP 5
#define H1 10
#define SEQ 500
#define EMB 300
#define THREADS 512
#define NKS 10                 // ceil(300/32) k-steps
#define PSTR 52                // proj LDS row stride (floats); 208 B rows, 16B aligned
#define BF_ELEMS (NKS * 4 * 64 * 8)   // 20480 bf16 = 40 KB

typedef float  f32x4  __attribute__((ext_vector_type(4)));
typedef __bf16 bf16x8 __attribute__((ext_vector_type(8)));
typedef short  s16x8  __attribute__((ext_vector_type(8)));
union frag_cast { s16x8 s; bf16x8 b; };

__device__ __host__ inline short f2bf_rne(float x) {
    unsigned u = __builtin_bit_cast(unsigned, x);
    u = u + 0x7FFF + ((u >> 16) & 1);
    return (short)(u >> 16);
}

// ---- prep: W[5][300][10] -> B-fragments Bf[ks][nt][lane][8] (bf16) ----
// k = ks*32 + (lane>>4)*8 + j ; col = nt*16 + (lane&15); zero if k>=300 or col>=50.
__global__ void build_bfrag(const float* __restrict__ Wg, short* __restrict__ Bf) {
    int i = blockIdx.x * blockDim.x + threadIdx.x;
    if (i >= BF_ELEMS) return;
    int j    = i & 7;
    int lane = (i >> 3) & 63;
    int nt   = (i >> 9) & 3;
    int ks   = i >> 11;
    int k    = ks * 32 + (lane >> 4) * 8 + j;
    int col  = nt * 16 + (lane & 15);
    float v = 0.f;
    if (k < EMB && col < 50) {
        int a = col / 10, h = col - a * 10;
        v = Wg[a * (EMB * H1) + k * H1 + h];
    }
    Bf[i] = f2bf_rne(v);
}

__global__ __launch_bounds__(THREADS, 4)
void arl_mfma(const float* __restrict__ doc,
              const short* __restrict__ Bf,
              const float* __restrict__ embG,
              float* __restrict__ out,
              int B) {
    __shared__ float SB[256 * PSTR];     // 53248 B: proj transpose buffer, then phase-2 overlay

    const int tid  = threadIdx.x;
    const int b    = blockIdx.x;
    const int lane = tid & 63;
    const int wave = tid >> 6;
    const int q    = lane & 15;          // intra-tile col / row selector
    const int kg   = lane >> 4;          // k-group (0..3)
    const int s    = tid;
    const bool active = (s < SEQ);

    const float* docB = doc + (size_t)b * (SEQ * EMB);

    f32x4 acc[4][4];                     // [mtile i][ntile]
    #pragma unroll
    for (int i = 0; i < 4; ++i)
        #pragma unroll
        for (int nt = 0; nt < 4; ++nt)
            acc[i][nt] = (f32x4){0.f, 0.f, 0.f, 0.f};

    // ---------------- phase 1: proj = doc x W via MFMA, k = 0..287 ----------------
    #pragma unroll 2
    for (int ks = 0; ks < NKS - 1; ++ks) {
        frag_cast bfr[4];
        const short* bp = Bf + ((size_t)(ks * 4) * 64 + lane) * 8;
        #pragma unroll
        for (int nt = 0; nt < 4; ++nt)
            bfr[nt].s = *reinterpret_cast<const s16x8*>(bp + nt * 64 * 8);

        #pragma unroll
        for (int i = 0; i < 4; ++i) {
            int row = (wave * 4 + i) * 16 + q;
            row = row < SEQ ? row : SEQ - 1;
            const float* ap = docB + (size_t)row * EMB + ks * 32 + kg * 8;
            float4 a0 = *reinterpret_cast<const float4*>(ap);
            float4 a1 = *reinterpret_cast<const float4*>(ap + 4);
            frag_cast af;
            af.s[0] = f2bf_rne(a0.x); af.s[1] = f2bf_rne(a0.y);
            af.s[2] = f2bf_rne(a0.z); af.s[3] = f2bf_rne(a0.w);
            af.s[4] = f2bf_rne(a1.x); af.s[5] = f2bf_rne(a1.y);
            af.s[6] = f2bf_rne(a1.z); af.s[7] = f2bf_rne(a1.w);
            #pragma unroll
            for (int nt = 0; nt < 4; ++nt)
                acc[i][nt] = __builtin_amdgcn_mfma_f32_16x16x32_bf16(
                    af.b, bfr[nt].b, acc[i][nt], 0, 0, 0);
        }
    }
    {   // tail ks = 9: k 288..299 valid; B-frag is zero for k>=300, so A there is don't-care.
        frag_cast bfr[4];
        const short* bp = Bf + ((size_t)(9 * 4) * 64 + lane) * 8;
        #pragma unroll
        for (int nt = 0; nt < 4; ++nt)
            bfr[nt].s = *reinterpret_cast<const s16x8*>(bp + nt * 64 * 8);

        #pragma unroll
        for (int i = 0; i < 4; ++i) {
            int row = (wave * 4 + i) * 16 + q;
            row = row < SEQ ? row : SEQ - 1;
            const float* ap = docB + (size_t)row * EMB + 288 + kg * 8;
            float4 a0 = {0.f, 0.f, 0.f, 0.f};
            float4 a1 = {0.f, 0.f, 0.f, 0.f};
            if (kg == 0) { a0 = *reinterpret_cast<const float4*>(ap);
                           a1 = *reinterpret_cast<const float4*>(ap + 4); }
            else if (kg == 1) { a0 = *reinterpret_cast<const float4*>(ap); }  // floats 296..299
            frag_cast af;
            af.s[0] = f2bf_rne(a0.x); af.s[1] = f2bf_rne(a0.y);
            af.s[2] = f2bf_rne(a0.z); af.s[3] = f2bf_rne(a0.w);
            af.s[4] = f2bf_rne(a1.x); af.s[5] = f2bf_rne(a1.y);
            af.s[6] = f2bf_rne(a1.z); af.s[7] = f2bf_rne(a1.w);
            #pragma unroll
            for (int nt = 0; nt < 4; ++nt)
                acc[i][nt] = __builtin_amdgcn_mfma_f32_16x16x32_bf16(
                    af.b, bfr[nt].b, acc[i][nt], 0, 0, 0);
        }
    }

    // ---------------- phase 1.5: transpose acc -> per-thread rows via LDS, 2 halves ----
    // C layout (verified m89): col = nt*16 + (lane&15); row = mtile*16 + kg*4 + r.
    float acc2[50];

    if (wave < 4) {
        #pragma unroll
        for (int i = 0; i < 4; ++i) {
            int rowL = (wave * 4 + i) * 16 + kg * 4;     // 0..255
            #pragma unroll
            for (int nt = 0; nt < 4; ++nt) {
                int col = nt * 16 + q;
                if (nt < 3 || q < 4) {                   // keep cols < 52
                    #pragma unroll
                    for (int r = 0; r < 4; ++r)
                        SB[(rowL + r) * PSTR + col] = acc[i][nt][r];
                }
            }
        }
    }
    __syncthreads();
    if (tid < 256) {
        const float* rp = &SB[tid * PSTR];
        #pragma unroll
        for (int j4 = 0; j4 < 12; ++j4) {
            float4 v = *reinterpret_cast<const float4*>(rp + j4 * 4);
            acc2[j4 * 4 + 0] = v.x; acc2[j4 * 4 + 1] = v.y;
            acc2[j4 * 4 + 2] = v.z; acc2[j4 * 4 + 3] = v.w;
        }
        float2 v2 = *reinterpret_cast<const float2*>(rp + 48);
        acc2[48] = v2.x; acc2[49] = v2.y;
    }
    __syncthreads();
    if (wave >= 4) {
        #pragma unroll
        for (int i = 0; i < 4; ++i) {
            int rowL = ((wave - 4) * 4 + i) * 16 + kg * 4;   // 0..255 (global rows 256..511)
            #pragma unroll
            for (int nt = 0; nt < 4; ++nt) {
                int col = nt * 16 + q;
                if (nt < 3 || q < 4) {
                    #pragma unroll
                    for (int r = 0; r < 4; ++r)
                        SB[(rowL + r) * PSTR + col] = acc[i][nt][r];
                }
            }
        }
    }
    __syncthreads();
    if (tid >= 256) {
        const float* rp = &SB[(tid - 256) * PSTR];
        #pragma unroll
        for (int j4 = 0; j4 < 12; ++j4) {
            float4 v = *reinterpret_cast<const float4*>(rp + j4 * 4);
            acc2[j4 * 4 + 0] = v.x; acc2[j4 * 4 + 1] = v.y;
            acc2[j4 * 4 + 2] = v.z; acc2[j4 * 4 + 3] = v.w;
        }
        float2 v2 = *reinterpret_cast<const float2*>(rp + 48);
        acc2[48] = v2.x; acc2[49] = v2.y;
    }
    __syncthreads();

    // ---------------- phase 2: scores, softmax, pooling (fully unrolled) --------------
    float* embS  = &SB[0];      // 150 floats
    float* Ubuf  = &SB[160];    // 5 * 513
    float* W3buf = &SB[2725];   // 5 * 501
    float* red   = &SB[5232];   // 8 * 52

    if (tid < NASP * 3 * H1) embS[tid] = embG[tid];
    __syncthreads();

    float uu[NASP], vv[NASP], ww[NASP];
    #pragma unroll
    for (int a = 0; a < NASP; ++a) {
        float su = 0.f, sv = 0.f, sw = 0.f;
        #pragma unroll
        for (int h = 0; h < H1; ++h) {
            float pj = acc2[a * 10 + h];
            su = fmaf(pj, embS[a * 30 + h],       su);
            sv = fmaf(pj, embS[a * 30 + 10 + h],  sv);
            sw = fmaf(pj, embS[a * 30 + 20 + h],  sw);
        }
        uu[a] = su; vv[a] = sv; ww[a] = sw;
    }
    if (active) {
        #pragma unroll
        for (int a = 0; a < NASP; ++a) {
            Ubuf[a * 513 + s + 1] = uu[a];   // read back at [s] -> u[s-1]
            W3buf[a * 501 + s]    = ww[a];   // read back at [s+1] -> w[s+1]
        }
    }
    if (tid == 0) {
        #pragma unroll
        for (int a = 0; a < NASP; ++a) { Ubuf[a * 513] = 0.f; W3buf[a * 501 + 500] = 0.f; }
    }
    __syncthreads();

    float sc[NASP];
    #pragma unroll
    for (int a = 0; a < NASP; ++a)
        sc[a] = active ? (Ubuf[a * 513 + s] + vv[a] + W3buf[a * 501 + s + 1]) : -1e30f;

    float m[NASP];
    #pragma unroll
    for (int a = 0; a < NASP; ++a) {
        float x = sc[a];
        #pragma unroll
        for (int off = 32; off > 0; off >>= 1) x = fmaxf(x, __shfl_xor(x, off));
        if (lane == 0) red[wave * NASP + a] = x;
    }
    __syncthreads();
    #pragma unroll
    for (int a = 0; a < NASP; ++a) {
        float mm = red[a];
        #pragma unroll
        for (int w2 = 1; w2 < 8; ++w2) mm = fmaxf(mm, red[w2 * NASP + a]);
        m[a] = mm;
    }
    __syncthreads();

    float p[NASP];
    #pragma unroll
    for (int a = 0; a < NASP; ++a) {
        float x = active ? __expf(sc[a] - m[a]) : 0.f;
        p[a] = x;
        float t = x;
        #pragma unroll
        for (int off = 32; off > 0; off >>= 1) t += __shfl_xor(t, off);
        if (lane == 0) red[wave * NASP + a] = t;
    }
    __syncthreads();
    float attnv[NASP];
    #pragma unroll
    for (int a = 0; a < NASP; ++a) {
        float ssum = 0.f;
        #pragma unroll
        for (int w2 = 0; w2 < 8; ++w2) ssum += red[w2 * NASP + a];
        attnv[a] = p[a] / ssum;
    }

    if (active) {
        #pragma unroll
        for (int a = 0; a < NASP; ++a)
            out[((size_t)b * NASP + a) * SEQ + s] = attnv[a];
    }
    __syncthreads();

    #pragma unroll
    for (int j = 0; j < 50; ++j) {
        float x = acc2[j] * attnv[j / 10];
        #pragma unroll
        for (int off = 32; off > 0; off >>= 1) x += __shfl_xor(x, off);
        if (lane == 0) red[wave * 52 + j] = x;
    }
    __syncthreads();
    if (tid < 50) {
        float ssum = 0.f;
        #pragma unroll
        for (int w2 = 0; w2 < 8; ++w2) ssum += red[w2 * 52 + tid];
        out[(size_t)B * NASP * SEQ + (size_t)b * 50 + tid] = ssum;
    }
}

extern "C" void kernel_launch(void* const* d_in, const int* in_sizes, int n_in,
                              void* d_out, int out_size, void* d_ws, size_t ws_size,
                              hipStream_t stream) {
    const float* doc = (const float*)d_in[0];
    const float* Wg  = (const float*)d_in[1];
    const float* emb = (const float*)d_in[2];
    float* out = (float*)d_out;
    short* Bf  = (short*)d_ws;                 // 40 KB scratch
    const int B = in_sizes[0] / (SEQ * EMB);   // 1024

    build_bfrag<<<dim3((BF_ELEMS + 255) / 256), dim3(256), 0, stream>>>(Wg, Bf);
    arl_mfma<<<dim3(B), dim3(THREADS), 0, stream>>>(doc, Bf, emb, out, B);
}

// Round 6
// 200.717 us; speedup vs baseline: 3.8037x; 1.1457x over previous
//
#include <hip/hip_runtime.h>
#include <hip/hip_bf16.h>

#define NASP 5
#define H1 10
#define SEQ 500
#define EMB 300
#define THREADS 512
#define NKS 10                 // ceil(300/32) k-steps
#define PSTR 52                // proj LDS row stride (floats); 208 B rows, 16B aligned
#define BF_ELEMS (NKS * 4 * 64 * 8)   // 20480 bf16 = 40 KB

typedef float  f32x4  __attribute__((ext_vector_type(4)));
typedef __bf16 bf16x8 __attribute__((ext_vector_type(8)));
typedef short  s16x8  __attribute__((ext_vector_type(8)));
union frag_cast { s16x8 s; bf16x8 b; };

__device__ __host__ inline short f2bf_rne(float x) {
    unsigned u = __builtin_bit_cast(unsigned, x);
    u = u + 0x7FFF + ((u >> 16) & 1);
    return (short)(u >> 16);
}

// ---- prep: W[5][300][10] -> B-fragments Bf[ks][nt][lane][8] (bf16) ----
// k = ks*32 + (lane>>4)*8 + j ; col = nt*16 + (lane&15); zero if k>=300 or col>=50.
__global__ void build_bfrag(const float* __restrict__ Wg, short* __restrict__ Bf) {
    int i = blockIdx.x * blockDim.x + threadIdx.x;
    if (i >= BF_ELEMS) return;
    int j    = i & 7;
    int lane = (i >> 3) & 63;
    int nt   = (i >> 9) & 3;
    int ks   = i >> 11;
    int k    = ks * 32 + (lane >> 4) * 8 + j;
    int col  = nt * 16 + (lane & 15);
    float v = 0.f;
    if (k < EMB && col < 50) {
        int a = col / 10, h = col - a * 10;
        v = Wg[a * (EMB * H1) + k * H1 + h];
    }
    Bf[i] = f2bf_rne(v);
}

__device__ inline bf16x8 cvt8(float4 a0, float4 a1) {
    bf16x8 r;
    r[0] = (__bf16)a0.x; r[1] = (__bf16)a0.y; r[2] = (__bf16)a0.z; r[3] = (__bf16)a0.w;
    r[4] = (__bf16)a1.x; r[5] = (__bf16)a1.y; r[6] = (__bf16)a1.z; r[7] = (__bf16)a1.w;
    return r;
}

__global__ __launch_bounds__(THREADS, 4)
void arl_mfma(const float* __restrict__ doc,
              const short* __restrict__ Bf,
              const float* __restrict__ embG,
              float* __restrict__ out,
              int B) {
    __shared__ float SB[256 * PSTR];     // 53248 B: proj transpose buffer, then phase-2 overlay

    const int tid  = threadIdx.x;
    const int b    = blockIdx.x;
    const int lane = tid & 63;
    const int wave = tid >> 6;
    const int q    = lane & 15;          // intra-tile col / row selector
    const int kg   = lane >> 4;          // k-group (0..3)
    const int s    = tid;
    const bool active = (s < SEQ);

    const float* docB = doc + (size_t)b * (SEQ * EMB);

    // per-i row base pointers (row does not depend on ks) — hoisted out of the k-loop
    const float* rowp[4];
    #pragma unroll
    for (int i = 0; i < 4; ++i) {
        int row = (wave * 4 + i) * 16 + q;
        row = row < SEQ ? row : SEQ - 1;
        rowp[i] = docB + (size_t)row * EMB + kg * 8;
    }

    f32x4 acc[4][4];                     // [mtile i][ntile]
    #pragma unroll
    for (int i = 0; i < 4; ++i)
        #pragma unroll
        for (int nt = 0; nt < 4; ++nt)
            acc[i][nt] = (f32x4){0.f, 0.f, 0.f, 0.f};

    // ---------------- phase 1: proj = doc x W via MFMA, k = 0..287 ----------------
    #pragma unroll 1
    for (int ks = 0; ks < NKS - 1; ++ks) {
        const int ko = ks * 32;

        frag_cast bfr[4];
        const short* bp = Bf + ((size_t)(ks * 4) * 64 + lane) * 8;
        #pragma unroll
        for (int nt = 0; nt < 4; ++nt)
            bfr[nt].s = *reinterpret_cast<const s16x8*>(bp + nt * 64 * 8);

        // issue-early: i=0,1 loads
        float4 s0a = *reinterpret_cast<const float4*>(rowp[0] + ko);
        float4 s0b = *reinterpret_cast<const float4*>(rowp[0] + ko + 4);
        float4 s1a = *reinterpret_cast<const float4*>(rowp[1] + ko);
        float4 s1b = *reinterpret_cast<const float4*>(rowp[1] + ko + 4);
        // issue i=2,3 loads BEFORE consuming i=0,1 (keep >=4 loads in flight)
        float4 s2a = *reinterpret_cast<const float4*>(rowp[2] + ko);
        float4 s2b = *reinterpret_cast<const float4*>(rowp[2] + ko + 4);
        float4 s3a = *reinterpret_cast<const float4*>(rowp[3] + ko);
        float4 s3b = *reinterpret_cast<const float4*>(rowp[3] + ko + 4);

        {
            bf16x8 af = cvt8(s0a, s0b);
            #pragma unroll
            for (int nt = 0; nt < 4; ++nt)
                acc[0][nt] = __builtin_amdgcn_mfma_f32_16x16x32_bf16(af, bfr[nt].b, acc[0][nt], 0, 0, 0);
        }
        {
            bf16x8 af = cvt8(s1a, s1b);
            #pragma unroll
            for (int nt = 0; nt < 4; ++nt)
                acc[1][nt] = __builtin_amdgcn_mfma_f32_16x16x32_bf16(af, bfr[nt].b, acc[1][nt], 0, 0, 0);
        }
        {
            bf16x8 af = cvt8(s2a, s2b);
            #pragma unroll
            for (int nt = 0; nt < 4; ++nt)
                acc[2][nt] = __builtin_amdgcn_mfma_f32_16x16x32_bf16(af, bfr[nt].b, acc[2][nt], 0, 0, 0);
        }
        {
            bf16x8 af = cvt8(s3a, s3b);
            #pragma unroll
            for (int nt = 0; nt < 4; ++nt)
                acc[3][nt] = __builtin_amdgcn_mfma_f32_16x16x32_bf16(af, bfr[nt].b, acc[3][nt], 0, 0, 0);
        }
    }
    {   // tail ks = 9: k 288..299 valid; B-frag is zero for k>=300, so A there is don't-care.
        frag_cast bfr[4];
        const short* bp = Bf + ((size_t)(9 * 4) * 64 + lane) * 8;
        #pragma unroll
        for (int nt = 0; nt < 4; ++nt)
            bfr[nt].s = *reinterpret_cast<const s16x8*>(bp + nt * 64 * 8);

        #pragma unroll
        for (int i = 0; i < 4; ++i) {
            const float* ap = rowp[i] + 288;
            float4 a0 = {0.f, 0.f, 0.f, 0.f};
            float4 a1 = {0.f, 0.f, 0.f, 0.f};
            if (kg == 0) { a0 = *reinterpret_cast<const float4*>(ap);
                           a1 = *reinterpret_cast<const float4*>(ap + 4); }
            else if (kg == 1) { a0 = *reinterpret_cast<const float4*>(ap); }  // floats 296..299
            bf16x8 af = cvt8(a0, a1);
            #pragma unroll
            for (int nt = 0; nt < 4; ++nt)
                acc[i][nt] = __builtin_amdgcn_mfma_f32_16x16x32_bf16(af, bfr[nt].b, acc[i][nt], 0, 0, 0);
        }
    }

    // ---------------- phase 1.5: transpose acc -> per-thread rows via LDS, 2 halves ----
    // C layout (verified m89): col = nt*16 + (lane&15); row = mtile*16 + kg*4 + r.
    float acc2[50];

    if (wave < 4) {
        #pragma unroll
        for (int i = 0; i < 4; ++i) {
            int rowL = (wave * 4 + i) * 16 + kg * 4;     // 0..255
            #pragma unroll
            for (int nt = 0; nt < 4; ++nt) {
                int col = nt * 16 + q;
                if (nt < 3 || q < 4) {                   // keep cols < 52
                    #pragma unroll
                    for (int r = 0; r < 4; ++r)
                        SB[(rowL + r) * PSTR + col] = acc[i][nt][r];
                }
            }
        }
    }
    __syncthreads();
    if (tid < 256) {
        const float* rp = &SB[tid * PSTR];
        #pragma unroll
        for (int j4 = 0; j4 < 12; ++j4) {
            float4 v = *reinterpret_cast<const float4*>(rp + j4 * 4);
            acc2[j4 * 4 + 0] = v.x; acc2[j4 * 4 + 1] = v.y;
            acc2[j4 * 4 + 2] = v.z; acc2[j4 * 4 + 3] = v.w;
        }
        float2 v2 = *reinterpret_cast<const float2*>(rp + 48);
        acc2[48] = v2.x; acc2[49] = v2.y;
    }
    __syncthreads();
    if (wave >= 4) {
        #pragma unroll
        for (int i = 0; i < 4; ++i) {
            int rowL = ((wave - 4) * 4 + i) * 16 + kg * 4;   // 0..255 (global rows 256..511)
            #pragma unroll
            for (int nt = 0; nt < 4; ++nt) {
                int col = nt * 16 + q;
                if (nt < 3 || q < 4) {
                    #pragma unroll
                    for (int r = 0; r < 4; ++r)
                        SB[(rowL + r) * PSTR + col] = acc[i][nt][r];
                }
            }
        }
    }
    __syncthreads();
    if (tid >= 256) {
        const float* rp = &SB[(tid - 256) * PSTR];
        #pragma unroll
        for (int j4 = 0; j4 < 12; ++j4) {
            float4 v = *reinterpret_cast<const float4*>(rp + j4 * 4);
            acc2[j4 * 4 + 0] = v.x; acc2[j4 * 4 + 1] = v.y;
            acc2[j4 * 4 + 2] = v.z; acc2[j4 * 4 + 3] = v.w;
        }
        float2 v2 = *reinterpret_cast<const float2*>(rp + 48);
        acc2[48] = v2.x; acc2[49] = v2.y;
    }
    __syncthreads();

    // ---------------- phase 2: scores, softmax, pooling (fully unrolled) --------------
    float* embS  = &SB[0];      // 150 floats
    float* Ubuf  = &SB[160];    // 5 * 513
    float* W3buf = &SB[2725];   // 5 * 501
    float* red   = &SB[5232];   // 8 * 52

    if (tid < NASP * 3 * H1) embS[tid] = embG[tid];
    __syncthreads();

    float uu[NASP], vv[NASP], ww[NASP];
    #pragma unroll
    for (int a = 0; a < NASP; ++a) {
        float su = 0.f, sv = 0.f, sw = 0.f;
        #pragma unroll
        for (int h = 0; h < H1; ++h) {
            float pj = acc2[a * 10 + h];
            su = fmaf(pj, embS[a * 30 + h],       su);
            sv = fmaf(pj, embS[a * 30 + 10 + h],  sv);
            sw = fmaf(pj, embS[a * 30 + 20 + h],  sw);
        }
        uu[a] = su; vv[a] = sv; ww[a] = sw;
    }
    if (active) {
        #pragma unroll
        for (int a = 0; a < NASP; ++a) {
            Ubuf[a * 513 + s + 1] = uu[a];   // read back at [s] -> u[s-1]
            W3buf[a * 501 + s]    = ww[a];   // read back at [s+1] -> w[s+1]
        }
    }
    if (tid == 0) {
        #pragma unroll
        for (int a = 0; a < NASP; ++a) { Ubuf[a * 513] = 0.f; W3buf[a * 501 + 500] = 0.f; }
    }
    __syncthreads();

    float sc[NASP];
    #pragma unroll
    for (int a = 0; a < NASP; ++a)
        sc[a] = active ? (Ubuf[a * 513 + s] + vv[a] + W3buf[a * 501 + s + 1]) : -1e30f;

    float m[NASP];
    #pragma unroll
    for (int a = 0; a < NASP; ++a) {
        float x = sc[a];
        #pragma unroll
        for (int off = 32; off > 0; off >>= 1) x = fmaxf(x, __shfl_xor(x, off));
        if (lane == 0) red[wave * NASP + a] = x;
    }
    __syncthreads();
    #pragma unroll
    for (int a = 0; a < NASP; ++a) {
        float mm = red[a];
        #pragma unroll
        for (int w2 = 1; w2 < 8; ++w2) mm = fmaxf(mm, red[w2 * NASP + a]);
        m[a] = mm;
    }
    __syncthreads();

    float p[NASP];
    #pragma unroll
    for (int a = 0; a < NASP; ++a) {
        float x = active ? __expf(sc[a] - m[a]) : 0.f;
        p[a] = x;
        float t = x;
        #pragma unroll
        for (int off = 32; off > 0; off >>= 1) t += __shfl_xor(t, off);
        if (lane == 0) red[wave * NASP + a] = t;
    }
    __syncthreads();
    float attnv[NASP];
    #pragma unroll
    for (int a = 0; a < NASP; ++a) {
        float ssum = 0.f;
        #pragma unroll
        for (int w2 = 0; w2 < 8; ++w2) ssum += red[w2 * NASP + a];
        attnv[a] = p[a] / ssum;
    }

    if (active) {
        #pragma unroll
        for (int a = 0; a < NASP; ++a)
            out[((size_t)b * NASP + a) * SEQ + s] = attnv[a];
    }
    __syncthreads();

    #pragma unroll
    for (int j = 0; j < 50; ++j) {
        float x = acc2[j] * attnv[j / 10];
        #pragma unroll
        for (int off = 32; off > 0; off >>= 1) x += __shfl_xor(x, off);
        if (lane == 0) red[wave * 52 + j] = x;
    }
    __syncthreads();
    if (tid < 50) {
        float ssum = 0.f;
        #pragma unroll
        for (int w2 = 0; w2 < 8; ++w2) ssum += red[w2 * 52 + tid];
        out[(size_t)B * NASP * SEQ + (size_t)b * 50 + tid] = ssum;
    }
}

extern "C" void kernel_launch(void* const* d_in, const int* in_sizes, int n_in,
                              void* d_out, int out_size, void* d_ws, size_t ws_size,
                              hipStream_t stream) {
    const float* doc = (const float*)d_in[0];
    const float* Wg  = (const float*)d_in[1];
    const float* emb = (const float*)d_in[2];
    float* out = (float*)d_out;
    short* Bf  = (short*)d_ws;                 // 40 KB scratch
    const int B = in_sizes[0] / (SEQ * EMB);   // 1024

    build_bfrag<<<dim3((BF_ELEMS + 255) / 256), dim3(256), 0, stream>>>(Wg, Bf);
    arl_mfma<<<dim3(B), dim3(THREADS), 0, stream>>>(doc, Bf, emb, out, B);
}

// Round 7
// 185.990 us; speedup vs baseline: 4.1048x; 1.0792x over previous
//
#include <hip/hip_runtime.h>
#include <hip/hip_bf16.h>

#define NASP 5
#define H1 10
#define SEQ 500
#define EMB 300
#define THREADS 512
#define NKS 10                 // ceil(300/32) k-steps
#define PSTR 52                // proj LDS row stride (floats); 208 B rows, 16B aligned
#define BF_ELEMS (NKS * 4 * 64 * 8)   // 20480 bf16 = 40 KB
#define P2STR 516              // pooling buffer row stride (floats)

typedef float  f32x4  __attribute__((ext_vector_type(4)));
typedef __bf16 bf16x8 __attribute__((ext_vector_type(8)));
typedef short  s16x8  __attribute__((ext_vector_type(8)));
union frag_cast { s16x8 s; bf16x8 b; };

__device__ __host__ inline short f2bf_rne(float x) {
    unsigned u = __builtin_bit_cast(unsigned, x);
    u = u + 0x7FFF + ((u >> 16) & 1);
    return (short)(u >> 16);
}

// ---- prep: W[5][300][10] -> B-fragments Bf[ks][nt][lane][8] (bf16) ----
// k = ks*32 + (lane>>4)*8 + j ; col = nt*16 + (lane&15); zero if k>=300 or col>=50.
__global__ void build_bfrag(const float* __restrict__ Wg, short* __restrict__ Bf) {
    int i = blockIdx.x * blockDim.x + threadIdx.x;
    if (i >= BF_ELEMS) return;
    int j    = i & 7;
    int lane = (i >> 3) & 63;
    int nt   = (i >> 9) & 3;
    int ks   = i >> 11;
    int k    = ks * 32 + (lane >> 4) * 8 + j;
    int col  = nt * 16 + (lane & 15);
    float v = 0.f;
    if (k < EMB && col < 50) {
        int a = col / 10, h = col - a * 10;
        v = Wg[a * (EMB * H1) + k * H1 + h];
    }
    Bf[i] = f2bf_rne(v);
}

__device__ inline bf16x8 cvt8(float4 a0, float4 a1) {
    bf16x8 r;
    r[0] = (__bf16)a0.x; r[1] = (__bf16)a0.y; r[2] = (__bf16)a0.z; r[3] = (__bf16)a0.w;
    r[4] = (__bf16)a1.x; r[5] = (__bf16)a1.y; r[6] = (__bf16)a1.z; r[7] = (__bf16)a1.w;
    return r;
}

__global__ __launch_bounds__(THREADS, 4)
void arl_mfma(const float* __restrict__ doc,
              const short* __restrict__ Bf,
              const float* __restrict__ embG,
              float* __restrict__ out,
              int B) {
    __shared__ float SB[256 * PSTR];     // 53248 B: transpose buffer / phase-2 overlay / pooling

    const int tid  = threadIdx.x;
    const int b    = blockIdx.x;
    const int lane = tid & 63;
    const int wave = tid >> 6;
    const int q    = lane & 15;          // intra-tile col / row selector
    const int kg   = lane >> 4;          // k-group (0..3)
    const int s    = tid;
    const bool active = (s < SEQ);

    const float* docB = doc + (size_t)b * (SEQ * EMB);

    // per-i row base pointers (row does not depend on ks) — hoisted out of the k-loop
    const float* rowp[4];
    #pragma unroll
    for (int i = 0; i < 4; ++i) {
        int row = (wave * 4 + i) * 16 + q;
        row = row < SEQ ? row : SEQ - 1;
        rowp[i] = docB + (size_t)row * EMB + kg * 8;
    }

    f32x4 acc[4][4];                     // [mtile i][ntile]
    #pragma unroll
    for (int i = 0; i < 4; ++i)
        #pragma unroll
        for (int nt = 0; nt < 4; ++nt)
            acc[i][nt] = (f32x4){0.f, 0.f, 0.f, 0.f};

    // ---------------- phase 1: proj = doc x W via MFMA, k = 0..287 ----------------
    #pragma unroll 1
    for (int ks = 0; ks < NKS - 1; ++ks) {
        const int ko = ks * 32;

        frag_cast bfr[4];
        const short* bp = Bf + ((size_t)(ks * 4) * 64 + lane) * 8;
        #pragma unroll
        for (int nt = 0; nt < 4; ++nt)
            bfr[nt].s = *reinterpret_cast<const s16x8*>(bp + nt * 64 * 8);

        // issue-early: i=0,1 loads
        float4 s0a = *reinterpret_cast<const float4*>(rowp[0] + ko);
        float4 s0b = *reinterpret_cast<const float4*>(rowp[0] + ko + 4);
        float4 s1a = *reinterpret_cast<const float4*>(rowp[1] + ko);
        float4 s1b = *reinterpret_cast<const float4*>(rowp[1] + ko + 4);
        // issue i=2,3 loads BEFORE consuming i=0,1 (keep >=4 loads in flight)
        float4 s2a = *reinterpret_cast<const float4*>(rowp[2] + ko);
        float4 s2b = *reinterpret_cast<const float4*>(rowp[2] + ko + 4);
        float4 s3a = *reinterpret_cast<const float4*>(rowp[3] + ko);
        float4 s3b = *reinterpret_cast<const float4*>(rowp[3] + ko + 4);

        {
            bf16x8 af = cvt8(s0a, s0b);
            #pragma unroll
            for (int nt = 0; nt < 4; ++nt)
                acc[0][nt] = __builtin_amdgcn_mfma_f32_16x16x32_bf16(af, bfr[nt].b, acc[0][nt], 0, 0, 0);
        }
        {
            bf16x8 af = cvt8(s1a, s1b);
            #pragma unroll
            for (int nt = 0; nt < 4; ++nt)
                acc[1][nt] = __builtin_amdgcn_mfma_f32_16x16x32_bf16(af, bfr[nt].b, acc[1][nt], 0, 0, 0);
        }
        {
            bf16x8 af = cvt8(s2a, s2b);
            #pragma unroll
            for (int nt = 0; nt < 4; ++nt)
                acc[2][nt] = __builtin_amdgcn_mfma_f32_16x16x32_bf16(af, bfr[nt].b, acc[2][nt], 0, 0, 0);
        }
        {
            bf16x8 af = cvt8(s3a, s3b);
            #pragma unroll
            for (int nt = 0; nt < 4; ++nt)
                acc[3][nt] = __builtin_amdgcn_mfma_f32_16x16x32_bf16(af, bfr[nt].b, acc[3][nt], 0, 0, 0);
        }
    }
    {   // tail ks = 9: k 288..299 valid; B-frag is zero for k>=300, so A there is don't-care.
        frag_cast bfr[4];
        const short* bp = Bf + ((size_t)(9 * 4) * 64 + lane) * 8;
        #pragma unroll
        for (int nt = 0; nt < 4; ++nt)
            bfr[nt].s = *reinterpret_cast<const s16x8*>(bp + nt * 64 * 8);

        #pragma unroll
        for (int i = 0; i < 4; ++i) {
            const float* ap = rowp[i] + 288;
            float4 a0 = {0.f, 0.f, 0.f, 0.f};
            float4 a1 = {0.f, 0.f, 0.f, 0.f};
            if (kg == 0) { a0 = *reinterpret_cast<const float4*>(ap);
                           a1 = *reinterpret_cast<const float4*>(ap + 4); }
            else if (kg == 1) { a0 = *reinterpret_cast<const float4*>(ap); }  // floats 296..299
            bf16x8 af = cvt8(a0, a1);
            #pragma unroll
            for (int nt = 0; nt < 4; ++nt)
                acc[i][nt] = __builtin_amdgcn_mfma_f32_16x16x32_bf16(af, bfr[nt].b, acc[i][nt], 0, 0, 0);
        }
    }

    // ---------------- phase 1.5: transpose acc -> per-thread rows via LDS, 2 halves ----
    // C layout (verified m89): col = nt*16 + (lane&15); row = mtile*16 + kg*4 + r.
    float acc2[50];

    if (wave < 4) {
        #pragma unroll
        for (int i = 0; i < 4; ++i) {
            int rowL = (wave * 4 + i) * 16 + kg * 4;     // 0..255
            #pragma unroll
            for (int nt = 0; nt < 4; ++nt) {
                int col = nt * 16 + q;
                if (nt < 3 || q < 4) {                   // keep cols < 52
                    #pragma unroll
                    for (int r = 0; r < 4; ++r)
                        SB[(rowL + r) * PSTR + col] = acc[i][nt][r];
                }
            }
        }
    }
    __syncthreads();
    if (tid < 256) {
        const float* rp = &SB[tid * PSTR];
        #pragma unroll
        for (int j4 = 0; j4 < 12; ++j4) {
            float4 v = *reinterpret_cast<const float4*>(rp + j4 * 4);
            acc2[j4 * 4 + 0] = v.x; acc2[j4 * 4 + 1] = v.y;
            acc2[j4 * 4 + 2] = v.z; acc2[j4 * 4 + 3] = v.w;
        }
        float2 v2 = *reinterpret_cast<const float2*>(rp + 48);
        acc2[48] = v2.x; acc2[49] = v2.y;
    }
    __syncthreads();
    if (wave >= 4) {
        #pragma unroll
        for (int i = 0; i < 4; ++i) {
            int rowL = ((wave - 4) * 4 + i) * 16 + kg * 4;   // 0..255 (global rows 256..511)
            #pragma unroll
            for (int nt = 0; nt < 4; ++nt) {
                int col = nt * 16 + q;
                if (nt < 3 || q < 4) {
                    #pragma unroll
                    for (int r = 0; r < 4; ++r)
                        SB[(rowL + r) * PSTR + col] = acc[i][nt][r];
                }
            }
        }
    }
    __syncthreads();
    if (tid >= 256) {
        const float* rp = &SB[(tid - 256) * PSTR];
        #pragma unroll
        for (int j4 = 0; j4 < 12; ++j4) {
            float4 v = *reinterpret_cast<const float4*>(rp + j4 * 4);
            acc2[j4 * 4 + 0] = v.x; acc2[j4 * 4 + 1] = v.y;
            acc2[j4 * 4 + 2] = v.z; acc2[j4 * 4 + 3] = v.w;
        }
        float2 v2 = *reinterpret_cast<const float2*>(rp + 48);
        acc2[48] = v2.x; acc2[49] = v2.y;
    }
    __syncthreads();

    // ---------------- phase 2: scores, softmax (emb via scalar loads from global) ----
    float* Ubuf  = &SB[160];    // 5 * 513
    float* W3buf = &SB[2725];   // 5 * 501
    float* red   = &SB[5232];   // 8 * 5

    // u/v/w partial dots: embG indices are compile-time -> wave-uniform s_loads
    float uu[NASP], vv[NASP], ww[NASP];
    #pragma unroll
    for (int a = 0; a < NASP; ++a) {
        float su = 0.f, sv = 0.f, sw = 0.f;
        #pragma unroll
        for (int h = 0; h < H1; ++h) {
            float pj = acc2[a * 10 + h];
            su = fmaf(pj, embG[a * 30 + h],       su);
            sv = fmaf(pj, embG[a * 30 + 10 + h],  sv);
            sw = fmaf(pj, embG[a * 30 + 20 + h],  sw);
        }
        uu[a] = su; vv[a] = sv; ww[a] = sw;
    }
    if (active) {
        #pragma unroll
        for (int a = 0; a < NASP; ++a) {
            Ubuf[a * 513 + s + 1] = uu[a];   // read back at [s] -> u[s-1]
            W3buf[a * 501 + s]    = ww[a];   // read back at [s+1] -> w[s+1]
        }
    }
    if (tid == 0) {
        #pragma unroll
        for (int a = 0; a < NASP; ++a) { Ubuf[a * 513] = 0.f; W3buf[a * 501 + 500] = 0.f; }
    }
    __syncthreads();

    float sc[NASP];
    #pragma unroll
    for (int a = 0; a < NASP; ++a)
        sc[a] = active ? (Ubuf[a * 513 + s] + vv[a] + W3buf[a * 501 + s + 1]) : -1e30f;

    float m[NASP];
    #pragma unroll
    for (int a = 0; a < NASP; ++a) {
        float x = sc[a];
        #pragma unroll
        for (int off = 32; off > 0; off >>= 1) x = fmaxf(x, __shfl_xor(x, off));
        if (lane == 0) red[wave * NASP + a] = x;
    }
    __syncthreads();
    #pragma unroll
    for (int a = 0; a < NASP; ++a) {
        float mm = red[a];
        #pragma unroll
        for (int w2 = 1; w2 < 8; ++w2) mm = fmaxf(mm, red[w2 * NASP + a]);
        m[a] = mm;
    }
    __syncthreads();

    float p[NASP];
    #pragma unroll
    for (int a = 0; a < NASP; ++a) {
        float x = active ? __expf(sc[a] - m[a]) : 0.f;
        p[a] = x;
        float t = x;
        #pragma unroll
        for (int off = 32; off > 0; off >>= 1) t += __shfl_xor(t, off);
        if (lane == 0) red[wave * NASP + a] = t;
    }
    __syncthreads();
    float attnv[NASP];
    #pragma unroll
    for (int a = 0; a < NASP; ++a) {
        float ssum = 0.f;
        #pragma unroll
        for (int w2 = 0; w2 < 8; ++w2) ssum += red[w2 * NASP + a];
        attnv[a] = p[a] / ssum;
    }

    if (active) {
        #pragma unroll
        for (int a = 0; a < NASP; ++a)
            out[((size_t)b * NASP + a) * SEQ + s] = attnv[a];
    }

    // ---------------- pooling: rep[j] = sum_s proj[s][j]*attn[j/10][s] ---------------
    // Scatter products to SB2[j][s] (25 j per half), gather-reduce with 400 threads.
    // For s>=500: attnv==0 so products are 0 — written too, harmless.
    const int jj = tid >> 4;            // 0..31 (only <25 used)
    const int g  = tid & 15;
    float* rep_out = out + (size_t)B * NASP * SEQ + (size_t)b * 50;

    #pragma unroll
    for (int half = 0; half < 2; ++half) {
        __syncthreads();                 // SB region handoff
        #pragma unroll
        for (int jr = 0; jr < 25; ++jr) {
            int j = half * 25 + jr;
            SB[jr * P2STR + s] = acc2[j] * attnv[j / 10];
        }
        __syncthreads();
        if (jj < 25) {
            const float* rp = &SB[jj * P2STR + g];
            float t = 0.f;
            #pragma unroll
            for (int mi = 0; mi < 32; ++mi) t += rp[mi * 16];
            t += __shfl_xor(t, 1);
            t += __shfl_xor(t, 2);
            t += __shfl_xor(t, 4);
            t += __shfl_xor(t, 8);
            if (g == 0) rep_out[half * 25 + jj] = t;
        }
    }
}

extern "C" void kernel_launch(void* const* d_in, const int* in_sizes, int n_in,
                              void* d_out, int out_size, void* d_ws, size_t ws_size,
                              hipStream_t stream) {
    const float* doc = (const float*)d_in[0];
    const float* Wg  = (const float*)d_in[1];
    const float* emb = (const float*)d_in[2];
    float* out = (float*)d_out;
    short* Bf  = (short*)d_ws;                 // 40 KB scratch
    const int B = in_sizes[0] / (SEQ * EMB);   // 1024

    build_bfrag<<<dim3((BF_ELEMS + 255) / 256), dim3(256), 0, stream>>>(Wg, Bf);
    arl_mfma<<<dim3(B), dim3(THREADS), 0, stream>>>(doc, Bf, emb, out, B);
}